// Round 1
// baseline (376.716 us; speedup 1.0000x reference)
//
#include <hip/hip_runtime.h>
#include <hip/hip_bf16.h>

// ProtoLayer: dists_to_protos[n][p] = |f_n|^2 + |p_p|^2 - 2 f_n.p_p  (N x P)
//             dists_to_latents      = transpose of the above          (P x N)
// N=65536, P=512, D=256, fp32 in/out. Memory-bound (~320 MB traffic).
// Cross term in bf16 MFMA (threshold is bf16-scale: 15.84), norms in fp32.

#define DD 256
#define PP 512
#define BN 64

typedef short bf16x8 __attribute__((ext_vector_type(8)));
typedef float f32x16 __attribute__((ext_vector_type(16)));

__device__ __forceinline__ unsigned short f2bf(float f) {
    unsigned int u = __builtin_bit_cast(unsigned int, f);
    u = (u + 0x7fffu + ((u >> 16) & 1u)) >> 16;   // RNE
    return (unsigned short)u;
}

// --- prep: prototypes fp32 -> bf16 (row-major [P][D]) + proto_sq fp32 ---
__global__ __launch_bounds__(256) void proto_prep(const float* __restrict__ proto,
                                                  unsigned short* __restrict__ bw,
                                                  float* __restrict__ psq) {
    const int w = threadIdx.x >> 6, lane = threadIdx.x & 63;
    const int row = blockIdx.x * 4 + w;                 // 128 blocks * 4 rows
    const float4 f = *(const float4*)(proto + (size_t)row * DD + lane * 4);
    ushort4 u;
    u.x = f2bf(f.x); u.y = f2bf(f.y); u.z = f2bf(f.z); u.w = f2bf(f.w);
    *(ushort4*)(bw + (size_t)row * DD + lane * 4) = u;
    float part = f.x * f.x + f.y * f.y + f.z * f.z + f.w * f.w;
    for (int o = 32; o > 0; o >>= 1) part += __shfl_xor(part, o, 64);
    if (lane == 0) psq[row] = part;
}

// --- main: block = 64 feature rows x all 512 prototypes ---
__global__ __launch_bounds__(512, 4) void proto_dist(
        const float* __restrict__ feat,
        const unsigned short* __restrict__ bw,
        const float* __restrict__ psq,
        float* __restrict__ out0,   // [N][512]
        float* __restrict__ out1,   // [512][N]
        int N) {
    // A slab 64 x 256 bf16, row padded +8 elems (16B) -> 4-way max b128 conflicts
    __shared__ unsigned short A_lds[BN * 264];          // 33792 B
    __shared__ float fsq[BN];

    const int tid = threadIdx.x;
    const int w = tid >> 6, lane = tid & 63;
    const int n0 = blockIdx.x * BN;

    // stage A: fp32 global -> bf16 LDS, one row (1024 B) per wave-instruction
    #pragma unroll
    for (int i = 0; i < 8; ++i) {
        const int row = i * 8 + w;
        const float4 f = *(const float4*)(feat + (size_t)(n0 + row) * DD + lane * 4);
        ushort4 u;
        u.x = f2bf(f.x); u.y = f2bf(f.y); u.z = f2bf(f.z); u.w = f2bf(f.w);
        *(ushort4*)&A_lds[row * 264 + lane * 4] = u;
        float part = f.x * f.x + f.y * f.y + f.z * f.z + f.w * f.w;
        for (int o = 32; o > 0; o >>= 1) part += __shfl_xor(part, o, 64);
        if (lane == 0) fsq[row] = part;
    }
    __syncthreads();

    const int r = w & 1;            // n-tile (32 rows)
    const int g = w >> 1;           // p-group (128 cols)
    const int colbase = g * 128;
    const int l31 = lane & 31;
    const int hi = lane >> 5;

    f32x16 acc[4];
    #pragma unroll
    for (int t = 0; t < 4; ++t)
        #pragma unroll
        for (int e = 0; e < 16; ++e) acc[t][e] = 0.0f;

    // A operand: A[m = lane&31][k = (lane>>5)*8 + j]  (analog of verified 16x16 map)
    const unsigned short* arow = &A_lds[(32 * r + l31) * 264 + hi * 8];
    // B operand: B[n = lane&31][k = (lane>>5)*8 + j], protos row-major in ws (L2-hot)
    const unsigned short* bbase = bw + (size_t)(colbase + l31) * DD + hi * 8;

    #pragma unroll 2
    for (int k0 = 0; k0 < DD; k0 += 16) {
        const bf16x8 a = *(const bf16x8*)(arow + k0);
        #pragma unroll
        for (int t = 0; t < 4; ++t) {
            const bf16x8 b = *(const bf16x8*)(bbase + (size_t)(32 * t) * DD + k0);
            acc[t] = __builtin_amdgcn_mfma_f32_32x32x16_bf16(a, b, acc[t], 0, 0, 0);
        }
    }

    __syncthreads();                 // done reading A_lds; reuse it for transpose
    float* trans = ((float*)A_lds) + w * (32 * 33);   // per-wave 32x33 fp32 = 4224 B

    #pragma unroll
    for (int t = 0; t < 4; ++t) {
        const int p = colbase + 32 * t + l31;
        const float psq_v = psq[p];
        // C/D layout (measured m74/m101): col = lane&31, row = (reg&3)+8*(reg>>2)+4*(lane>>5)
        #pragma unroll
        for (int reg = 0; reg < 16; ++reg) {
            const int n_l = (reg & 3) + 8 * (reg >> 2) + 4 * hi;
            const int n_b = 32 * r + n_l;
            const float dist = fsq[n_b] + psq_v - 2.0f * acc[t][reg];
            out0[(size_t)(n0 + n_b) * PP + p] = dist;     // contiguous in p
            trans[l31 * 33 + n_l] = dist;                 // conflict-free (33 pad)
        }
        // same-wave LDS exchange: lgkmcnt ordering, no barrier needed
        #pragma unroll
        for (int j = 0; j < 16; ++j) {
            const int p_row = 2 * j + hi;
            const float v = trans[p_row * 33 + l31];
            out1[(size_t)(colbase + 32 * t + p_row) * N + (n0 + 32 * r + l31)] = v;
        }
    }
}

extern "C" void kernel_launch(void* const* d_in, const int* in_sizes, int n_in,
                              void* d_out, int out_size, void* d_ws, size_t ws_size,
                              hipStream_t stream) {
    const float* feat = (const float*)d_in[0];
    const float* proto = (const float*)d_in[1];
    const int N = in_sizes[0] / DD;          // 65536

    unsigned short* bw = (unsigned short*)d_ws;              // 512*256*2 = 256 KB
    float* psq = (float*)((char*)d_ws + (size_t)PP * DD * 2);  // +2 KB

    float* out0 = (float*)d_out;
    float* out1 = out0 + (size_t)N * PP;

    proto_prep<<<PP / 4, 256, 0, stream>>>(proto, bw, psq);
    proto_dist<<<N / BN, 512, 0, stream>>>(feat, bw, psq, out0, out1, N);
}

// Round 3
// 357.756 us; speedup vs baseline: 1.0530x; 1.0530x over previous
//
#include <hip/hip_runtime.h>
#include <hip/hip_bf16.h>

// ProtoLayer: dists_to_protos[n][p] = |f_n|^2 + |p_p|^2 - 2 f_n.p_p  (N x P)
//             dists_to_latents      = transpose of the above          (P x N)
// N=65536, P=512, D=256, fp32 in/out. Memory-bound (~332 MB traffic, floor ~53us).
// Cross term in bf16 MFMA (threshold 15.84 is bf16-scale; measured absmax 4.0).
// R2: nontemporal stores (keep B L2-hot, avoid 256KB-stride L2 set thrash),
//     float4 out1 stores via PAD=36 LDS transpose, nontemporal feat loads.
// R3: use ext_vector_type f32x4 for nontemporal builtins (HIP float4 is a
//     struct — rejected by __builtin_nontemporal_*).

#define DD 256
#define PP 512
#define BN 64
#define TP 36   // transpose tile pad: 32+4 keeps 16B alignment for b128 ops

typedef short bf16x8 __attribute__((ext_vector_type(8)));
typedef float f32x16 __attribute__((ext_vector_type(16)));
typedef float f32x4 __attribute__((ext_vector_type(4)));
typedef unsigned short u16x4 __attribute__((ext_vector_type(4)));

__device__ __forceinline__ unsigned short f2bf(float f) {
    unsigned int u = __builtin_bit_cast(unsigned int, f);
    u = (u + 0x7fffu + ((u >> 16) & 1u)) >> 16;   // RNE
    return (unsigned short)u;
}

// --- prep: prototypes fp32 -> bf16 (row-major [P][D]) + proto_sq fp32 ---
__global__ __launch_bounds__(256) void proto_prep(const float* __restrict__ proto,
                                                  unsigned short* __restrict__ bw,
                                                  float* __restrict__ psq) {
    const int w = threadIdx.x >> 6, lane = threadIdx.x & 63;
    const int row = blockIdx.x * 4 + w;                 // 128 blocks * 4 rows
    const f32x4 f = *(const f32x4*)(proto + (size_t)row * DD + lane * 4);
    u16x4 u;
    u.x = f2bf(f.x); u.y = f2bf(f.y); u.z = f2bf(f.z); u.w = f2bf(f.w);
    *(u16x4*)(bw + (size_t)row * DD + lane * 4) = u;
    float part = f.x * f.x + f.y * f.y + f.z * f.z + f.w * f.w;
    for (int o = 32; o > 0; o >>= 1) part += __shfl_xor(part, o, 64);
    if (lane == 0) psq[row] = part;
}

// --- main: block = 64 feature rows x all 512 prototypes ---
__global__ __launch_bounds__(512, 4) void proto_dist(
        const float* __restrict__ feat,
        const unsigned short* __restrict__ bw,
        const float* __restrict__ psq,
        float* __restrict__ out0,   // [N][512]
        float* __restrict__ out1,   // [512][N]
        int N) {
    // Shared region serves two phases:
    //  phase 1: A slab 64 x 264 bf16 (33792 B), row pad +8 elems
    //  phase 2: per-wave 32x36 fp32 transpose tiles (8 * 4608 = 36864 B)
    __shared__ unsigned char S[8 * 32 * TP * 4];        // 36864 B
    __shared__ float fsq[BN];
    unsigned short* A_lds = (unsigned short*)S;

    const int tid = threadIdx.x;
    const int w = tid >> 6, lane = tid & 63;
    const int n0 = blockIdx.x * BN;

    // stage A: fp32 global -> bf16 LDS (nontemporal: feat read exactly once)
    #pragma unroll
    for (int i = 0; i < 8; ++i) {
        const int row = i * 8 + w;
        const f32x4 f = __builtin_nontemporal_load(
            (const f32x4*)(feat + (size_t)(n0 + row) * DD + lane * 4));
        u16x4 u;
        u.x = f2bf(f.x); u.y = f2bf(f.y); u.z = f2bf(f.z); u.w = f2bf(f.w);
        *(u16x4*)&A_lds[row * 264 + lane * 4] = u;
        float part = f.x * f.x + f.y * f.y + f.z * f.z + f.w * f.w;
        for (int o = 32; o > 0; o >>= 1) part += __shfl_xor(part, o, 64);
        if (lane == 0) fsq[row] = part;
    }
    __syncthreads();

    const int r = w & 1;            // n-tile (32 rows)
    const int g = w >> 1;           // p-group (128 cols)
    const int colbase = g * 128;
    const int l31 = lane & 31;
    const int hi = lane >> 5;

    f32x16 acc[4];
    #pragma unroll
    for (int t = 0; t < 4; ++t)
        #pragma unroll
        for (int e = 0; e < 16; ++e) acc[t][e] = 0.0f;

    // A operand: A[m = lane&31][k = (lane>>5)*8 + j]
    const unsigned short* arow = &A_lds[(32 * r + l31) * 264 + hi * 8];
    // B operand: B[n = lane&31][k = (lane>>5)*8 + j], protos row-major, L2-hot
    const unsigned short* bbase = bw + (size_t)(colbase + l31) * DD + hi * 8;

    #pragma unroll 2
    for (int k0 = 0; k0 < DD; k0 += 16) {
        const bf16x8 a = *(const bf16x8*)(arow + k0);
        #pragma unroll
        for (int t = 0; t < 4; ++t) {
            const bf16x8 b = *(const bf16x8*)(bbase + (size_t)(32 * t) * DD + k0);
            acc[t] = __builtin_amdgcn_mfma_f32_32x32x16_bf16(a, b, acc[t], 0, 0, 0);
        }
    }

    __syncthreads();                 // done reading A_lds; reuse for transpose
    float* trans = ((float*)S) + w * (32 * TP);   // per-wave 32x36 fp32

    // cache fsq values for this wave's 32-row stripe
    float fsq_q[4][4];
    #pragma unroll
    for (int q = 0; q < 4; ++q)
        #pragma unroll
        for (int e = 0; e < 4; ++e)
            fsq_q[q][e] = fsq[32 * r + e + 8 * q + 4 * hi];

    float* out0_base = out0 + (size_t)(n0 + 32 * r) * PP;

    #pragma unroll
    for (int t = 0; t < 4; ++t) {
        const int p = colbase + 32 * t + l31;
        const float psq_v = psq[p];
        // C/D layout (m74/m101): col = lane&31, row = (reg&3)+8*(reg>>2)+4*(lane>>5)
        #pragma unroll
        for (int q = 0; q < 4; ++q) {
            f32x4 d;
            #pragma unroll
            for (int e = 0; e < 4; ++e) {
                const int reg = 4 * q + e;
                const int n_l = e + 8 * q + 4 * hi;
                const float dist = fsq_q[q][e] + psq_v - 2.0f * acc[t][reg];
                d[e] = dist;
                __builtin_nontemporal_store(dist, out0_base + (size_t)n_l * PP + p);
            }
            // p-major transpose tile: row = p-local (l31), 4 consecutive n
            *(f32x4*)&trans[l31 * TP + 8 * q + 4 * hi] = d;
        }
        // same-wave LDS exchange (compiler inserts lgkmcnt); read float4 along n
        #pragma unroll
        for (int j = 0; j < 4; ++j) {
            const int p_row = j * 8 + (lane >> 3);       // 8 p-rows per instr
            const int n_off = (lane & 7) * 4;            // 8 lanes * 4 n = 32 n
            const f32x4 v = *(const f32x4*)&trans[p_row * TP + n_off];
            __builtin_nontemporal_store(v,
                (f32x4*)(out1 + (size_t)(colbase + 32 * t + p_row) * N
                               + (n0 + 32 * r + n_off)));
        }
    }
}

extern "C" void kernel_launch(void* const* d_in, const int* in_sizes, int n_in,
                              void* d_out, int out_size, void* d_ws, size_t ws_size,
                              hipStream_t stream) {
    const float* feat = (const float*)d_in[0];
    const float* proto = (const float*)d_in[1];
    const int N = in_sizes[0] / DD;          // 65536

    unsigned short* bw = (unsigned short*)d_ws;                // 512*256*2 = 256 KB
    float* psq = (float*)((char*)d_ws + (size_t)PP * DD * 2);  // +2 KB

    float* out0 = (float*)d_out;
    float* out1 = out0 + (size_t)N * PP;

    proto_prep<<<PP / 4, 256, 0, stream>>>(proto, bw, psq);
    proto_dist<<<N / BN, 512, 0, stream>>>(feat, bw, psq, out0, out1, N);
}